// Round 6
// baseline (52892.822 us; speedup 1.0000x reference)
//
#include <hip/hip_runtime.h>
#include <stdint.h>
#include <math.h>

#define HD 1024
#define BB 8
#define LL 2048
#define NBLK 256
#define NTHR 512

typedef unsigned short u16;
typedef unsigned int u32;
typedef unsigned long long u64;

using bf16x8 = __attribute__((ext_vector_type(8))) short;
using f32x4  = __attribute__((ext_vector_type(4))) float;

__device__ __forceinline__ u16 f2bf(float f) {
  u32 x = __float_as_uint(f);
  x += 0x7fffu + ((x >> 16) & 1u);
  return (u16)(x >> 16);
}
__device__ __forceinline__ float bf2f(u16 u) {
  return __uint_as_float(((u32)u) << 16);
}
__device__ __forceinline__ float dot4(float4 a, float4 b) {
  return fmaf(a.x, b.x, fmaf(a.y, b.y, fmaf(a.z, b.z, a.w * b.w)));
}
__device__ __forceinline__ float sigmoidf(float x) { return 1.f / (1.f + expf(-x)); }

// unpack 4 bf16 (in u64) -> float4
__device__ __forceinline__ float4 unpk(u64 v) {
  u32 lo = (u32)v, hi = (u32)(v >> 32);
  float4 f;
  f.x = __uint_as_float(lo << 16);
  f.y = __uint_as_float(lo & 0xffff0000u);
  f.z = __uint_as_float(hi << 16);
  f.w = __uint_as_float(hi & 0xffff0000u);
  return f;
}

// ---- coherent LLC (sc1) accesses via relaxed agent atomics ----
__device__ __forceinline__ u64 cload8(const u64* p) {
  return __hip_atomic_load(p, __ATOMIC_RELAXED, __HIP_MEMORY_SCOPE_AGENT);
}
__device__ __forceinline__ void cstore8(u64* p, u64 v) {
  __hip_atomic_store(p, v, __ATOMIC_RELAXED, __HIP_MEMORY_SCOPE_AGENT);
}

// ---- barrier: 16 groups x 16 blocks; arrive=1 RMW; wait=direct 16-line poll ----
// group line (inst,g) at u32 index (inst*16+g)*16 ; 4 cycling instances, monotonic.
__device__ __forceinline__ void bar_arrive(u32* bar, int n, int grp) {
  int inst = n & 3;
  __hip_atomic_fetch_add(&bar[(inst * 16 + grp) * 16], 1u,
                         __ATOMIC_RELAXED, __HIP_MEMORY_SCOPE_AGENT);
}
__device__ __forceinline__ void bar_wait16(u32* bar, int n, int ln) {
  int inst = n & 3;
  u32 tgt = (u32)((n >> 2) + 1) * 16u;
  for (;;) {
    u32 v = tgt;
    if (ln < 16)
      v = __hip_atomic_load(&bar[(inst * 16 + ln) * 16],
                            __ATOMIC_RELAXED, __HIP_MEMORY_SCOPE_AGENT);
    if (__ballot(v >= tgt) == ~0ull) break;
    __builtin_amdgcn_s_sleep(1);
  }
}

// ---------------- input LN: x [16384,1024] f32 -> xn bf16 ----------------
__global__ __launch_bounds__(256) void k_ln_x(const float* __restrict__ x,
    const float* __restrict__ g, const float* __restrict__ b,
    u16* __restrict__ xn) {
  int row = blockIdx.x;
  int t = threadIdx.x;
  const float4* xr = (const float4*)(x + (size_t)row * HD);
  float4 v = xr[t];
  float s = v.x + v.y + v.z + v.w;
  float ss = v.x * v.x + v.y * v.y + v.z * v.z + v.w * v.w;
#pragma unroll
  for (int off = 32; off; off >>= 1) { s += __shfl_down(s, off); ss += __shfl_down(ss, off); }
  __shared__ float red[8];
  if ((t & 63) == 0) { red[t >> 6] = s; red[4 + (t >> 6)] = ss; }
  __syncthreads();
  s = red[0] + red[1] + red[2] + red[3];
  ss = red[4] + red[5] + red[6] + red[7];
  float m = s * (1.0f / HD);
  float rstd = rsqrtf(ss * (1.0f / HD) - m * m + 1e-5f);
  float4 gv = ((const float4*)g)[t];
  float4 bv = ((const float4*)b)[t];
  ushort4 o;
  o.x = f2bf((v.x - m) * rstd * gv.x + bv.x);
  o.y = f2bf((v.y - m) * rstd * gv.y + bv.y);
  o.z = f2bf((v.z - m) * rstd * gv.z + bv.z);
  o.w = f2bf((v.w - m) * rstd * gv.w + bv.w);
  *(ushort4*)(xn + (size_t)row * HD + t * 4) = o;
}

// ---------------- output LN, in place on f32 rows ----------------
__global__ __launch_bounds__(256) void k_out_ln(float* __restrict__ y,
    const float* __restrict__ g, const float* __restrict__ b) {
  int row = blockIdx.x;
  int t = threadIdx.x;
  float4* yr = (float4*)(y + (size_t)row * HD);
  float4 v = yr[t];
  float s = v.x + v.y + v.z + v.w;
  float ss = v.x * v.x + v.y * v.y + v.z * v.z + v.w * v.w;
#pragma unroll
  for (int off = 32; off; off >>= 1) { s += __shfl_down(s, off); ss += __shfl_down(ss, off); }
  __shared__ float red[8];
  if ((t & 63) == 0) { red[t >> 6] = s; red[4 + (t >> 6)] = ss; }
  __syncthreads();
  s = red[0] + red[1] + red[2] + red[3];
  ss = red[4] + red[5] + red[6] + red[7];
  float m = s * (1.0f / HD);
  float rstd = rsqrtf(ss * (1.0f / HD) - m * m + 1e-5f);
  float4 gv = ((const float4*)g)[t];
  float4 bv = ((const float4*)b)[t];
  float4 o;
  o.x = (v.x - m) * rstd * gv.x + bv.x;
  o.y = (v.y - m) * rstd * gv.y + bv.y;
  o.z = (v.z - m) * rstd * gv.z + bv.z;
  o.w = (v.w - m) * rstd * gv.w + bv.w;
  yr[t] = o;
}

// ---------------- pack input-side weights to bf16: win=[3][1024][1024] ----
__global__ __launch_bounds__(256) void k_pack_win(const float* __restrict__ wz,
    const float* __restrict__ wr, const float* __restrict__ wh,
    u16* __restrict__ win) {
  int gid = blockIdx.x;           // 0..3071
  int gate = gid >> 10, o = gid & 1023;
  const float* w = (gate == 0) ? wz : ((gate == 1) ? wr : wh);
  const float* row = w + (size_t)o * (2 * HD);
  int t = threadIdx.x;
  float4 a = ((const float4*)row)[t];
  ushort4 ua;
  ua.x = f2bf(a.x); ua.y = f2bf(a.y); ua.z = f2bf(a.z); ua.w = f2bf(a.w);
  *(ushort4*)(win + (size_t)gid * HD + t * 4) = ua;
}

// ---------------- precompute folded recurrent weights (fp32) --------------
__global__ __launch_bounds__(256) void k_prep_rec(const float* __restrict__ wz,
    const float* __restrict__ wr, const float* __restrict__ wh,
    const float* __restrict__ g_st, const float* __restrict__ b_st,
    float* __restrict__ W1p, float* __restrict__ Whg, float* __restrict__ Whb,
    float* __restrict__ Sg, float* __restrict__ Sb) {
  int gid = blockIdx.x;
  int gate = gid >> 10, o = gid & 1023;
  const float* w = (gate == 0) ? wz : ((gate == 1) ? wr : wh);
  int t = threadIdx.x;
  float4 wv = ((const float4*)(w + (size_t)o * (2 * HD) + HD))[t];
  float4 gv = ((const float4*)g_st)[t];
  float4 bv = ((const float4*)b_st)[t];
  float4 wg, wb;
  wg.x = wv.x * gv.x; wg.y = wv.y * gv.y; wg.z = wv.z * gv.z; wg.w = wv.w * gv.w;
  wb.x = wv.x * bv.x; wb.y = wv.y * bv.y; wb.z = wv.z * bv.z; wb.w = wv.w * bv.w;
  if (gate < 2) {
    ((float4*)(W1p + ((size_t)gate << 20) + ((size_t)o << 10)))[t] = wg;
    float sg = wg.x + wg.y + wg.z + wg.w;
    float sb = wb.x + wb.y + wb.z + wb.w;
#pragma unroll
    for (int off = 32; off; off >>= 1) { sg += __shfl_down(sg, off); sb += __shfl_down(sb, off); }
    __shared__ float red[8];
    if ((t & 63) == 0) { red[t >> 6] = sg; red[4 + (t >> 6)] = sb; }
    __syncthreads();
    if (t == 0) {
      Sg[gate * HD + o] = red[0] + red[1] + red[2] + red[3];
      Sb[gate * HD + o] = red[4] + red[5] + red[6] + red[7];
    }
  } else {
    ((float4*)(Whg + ((size_t)o << 10)))[t] = wg;
    ((float4*)(Whb + ((size_t)o << 10)))[t] = wb;
  }
}

// ---------------- bf16 MFMA GEMM: C[16384,3072] = A[16384,1024] * B[3072,1024]^T
__global__ __launch_bounds__(256) void k_gemm(const u16* __restrict__ A,
    const u16* __restrict__ Bw, u16* __restrict__ C) {
  __shared__ u16 As[128 * 32];
  __shared__ u16 Bs[128 * 32];
  int tid = threadIdx.x;
  int bx = blockIdx.x % 24;       // N tile
  int by = blockIdx.x / 24;       // M tile
  int m0 = by * 128, n0 = bx * 128;
  int lane = tid & 63, wave = tid >> 6;
  int wr = wave >> 1, wc = wave & 1;
  int rl = lane & 15, kq = (lane >> 4) * 8;
  f32x4 acc[4][4] = {};
  int srow = tid >> 2, skb = (tid & 3) * 8;
  for (int k0 = 0; k0 < 1024; k0 += 32) {
    __syncthreads();
#pragma unroll
    for (int i = 0; i < 2; i++) {
      int row = srow + i * 64;
      uint4 av = *(const uint4*)(A + (size_t)(m0 + row) * 1024 + k0 + skb);
      *(uint4*)(As + row * 32 + skb) = av;
      uint4 bv = *(const uint4*)(Bw + (size_t)(n0 + row) * 1024 + k0 + skb);
      *(uint4*)(Bs + row * 32 + skb) = bv;
    }
    __syncthreads();
    bf16x8 af[4], bg[4];
#pragma unroll
    for (int mi = 0; mi < 4; mi++)
      af[mi] = *(const bf16x8*)(As + (wr * 64 + mi * 16 + rl) * 32 + kq);
#pragma unroll
    for (int ni = 0; ni < 4; ni++)
      bg[ni] = *(const bf16x8*)(Bs + (wc * 64 + ni * 16 + rl) * 32 + kq);
#pragma unroll
    for (int mi = 0; mi < 4; mi++)
#pragma unroll
      for (int ni = 0; ni < 4; ni++)
        acc[mi][ni] = __builtin_amdgcn_mfma_f32_16x16x32_bf16(af[mi], bg[ni], acc[mi][ni], 0, 0, 0);
  }
  int rowq = (lane >> 4) * 4;
#pragma unroll
  for (int mi = 0; mi < 4; mi++)
#pragma unroll
    for (int ni = 0; ni < 4; ni++)
#pragma unroll
      for (int r = 0; r < 4; r++) {
        int row = m0 + wr * 64 + mi * 16 + rowq + r;
        int col = n0 + wc * 64 + ni * 16 + rl;
        C[(size_t)row * 3072 + col] = f2bf(acc[mi][ni][r]);
      }
}

// ---------------- init bf16 h broadcast from fp32 h0 ----------------
__global__ __launch_bounds__(256) void k_init_h(const float* __restrict__ h0,
    u16* __restrict__ hg) {
  int i = blockIdx.x * 256 + threadIdx.x;   // 4096 threads, 2 elems each
  float2 v = ((const float2*)h0)[i];
  ((u32*)hg)[i] = (u32)f2bf(v.x) | ((u32)f2bf(v.y) << 16);
}

// ---------------- persistent recurrence kernel ----------------------------
// 256 blocks x 512 threads; block bl owns outputs [bl*4, bl*4+4) per gate.
// Wave w owns batch w. Lane = (oi<<4)|p : oi selects output, p is k-slice lane.
// h/r broadcast via bf16 in LLC; master h state replicated fp32 in registers.
__global__ __launch_bounds__(NTHR, 2) void k_rec(
    u16* __restrict__ hglob, u16* __restrict__ rglob,
    const float* __restrict__ W1p, const float* __restrict__ Whg,
    const float* __restrict__ Whb, const float* __restrict__ Sg,
    const float* __restrict__ Sb, const u16* __restrict__ gx,
    const float* __restrict__ bz, const float* __restrict__ br,
    const float* __restrict__ bh, const float* __restrict__ h0,
    float* __restrict__ out, float* __restrict__ hfin,
    u32* __restrict__ bar) {
  const int t = threadIdx.x;
  const int bl = blockIdx.x;
  const int grp = bl >> 4;
  const int o0 = bl * 4;
  const int w = t >> 6, ln = t & 63;
  const int p = ln & 15, oi = ln >> 4;
  const int o = o0 + oi;

  const float4* wZ = (const float4*)(W1p + ((size_t)o << 10));
  const float4* wR = (const float4*)(W1p + (1u << 20) + ((size_t)o << 10));
  const float4* wG = (const float4*)(Whg + ((size_t)o << 10));
  const float4* wB = (const float4*)(Whb + ((size_t)o << 10));
  const float sgZ = Sg[o],      sbZ = Sb[o],      biZ = bz[o];
  const float sgR = Sg[HD + o], sbR = Sb[HD + o], biR = br[o];
  const float bhc = bh[o];
  const u64* hsrc = (const u64*)hglob + (size_t)w * 256 + p;
  const u64* rsrc = (const u64*)rglob + (size_t)w * 256 + p;
  u64* hdst = (u64*)hglob + (size_t)w * 256 + bl;
  u64* rdst = (u64*)rglob + (size_t)w * 256 + bl;
  const u16* gp = gx + ((size_t)w * LL) * 3072 + o;   // +0:z, +HD:r, +2HD:h
  float* outp = out + ((size_t)w * LL) * HD + o;

  float ho = h0[w * HD + o];        // master state, replicated in all 16 lanes
  u16 gZ = gp[0], gR = gp[HD], gH = gp[2 * HD];   // step-0 gx prefetch
  gp += 3072;

  for (int step = 0; step < LL; step++) {
    // ---- stage h slice -> registers + LN stats (16-lane reduce) ----
    float4 hreg[16];
#pragma unroll
    for (int j = 0; j < 16; j++) hreg[j] = unpk(cload8(hsrc + j * 16));
    float s = 0.f, ss = 0.f;
#pragma unroll
    for (int j = 0; j < 16; j++) {
      float4 v = hreg[j];
      s += (v.x + v.y) + (v.z + v.w);
      ss = fmaf(v.x, v.x, fmaf(v.y, v.y, fmaf(v.z, v.z, fmaf(v.w, v.w, ss))));
    }
    s += __shfl_xor(s, 1);  ss += __shfl_xor(ss, 1);
    s += __shfl_xor(s, 2);  ss += __shfl_xor(ss, 2);
    s += __shfl_xor(s, 4);  ss += __shfl_xor(ss, 4);
    s += __shfl_xor(s, 8);  ss += __shfl_xor(ss, 8);
    float m = s * (1.0f / HD);
    float rstd = rsqrtf(ss * (1.0f / HD) - m * m + 1e-5f);
    // ---- r gate: compute, publish, arrive ----
    float accR = 0.f;
#pragma unroll
    for (int j = 0; j < 16; j++) accR += dot4(wR[p + j * 16], hreg[j]);
    accR += __shfl_xor(accR, 1);
    accR += __shfl_xor(accR, 2);
    accR += __shfl_xor(accR, 4);
    accR += __shfl_xor(accR, 8);
    float sigR = sigmoidf(fmaf(rstd, accR, fmaf(-m * rstd, sgR, sbR)) + bf2f(gR) + biR);
    {
      u32 mr = f2bf(sigR);
      u32 v1 = __shfl((int)mr, 16), v2 = __shfl((int)mr, 32), v3 = __shfl((int)mr, 48);
      if (ln == 0)
        cstore8(rdst, (u64)mr | ((u64)v1 << 16) | ((u64)v2 << 32) | ((u64)v3 << 48));
    }
    __syncthreads();                       // drains the sc1 store (vmcnt 0)
    if (t == 0) bar_arrive(bar, 2 * step, grp);
    // ---- z gate overlapped with barrier-1 wait ----
    float accZ = 0.f;
#pragma unroll
    for (int j = 0; j < 16; j++) accZ += dot4(wZ[p + j * 16], hreg[j]);
    accZ += __shfl_xor(accZ, 1);
    accZ += __shfl_xor(accZ, 2);
    accZ += __shfl_xor(accZ, 4);
    accZ += __shfl_xor(accZ, 8);
    float zv = sigmoidf(fmaf(rstd, accZ, fmaf(-m * rstd, sgZ, sbZ)) + bf2f(gZ) + biZ);
    if (w == 0) bar_wait16(bar, 2 * step, ln);
    __syncthreads();
    // ---- stage r slice -> registers ----
    float4 rreg[16];
#pragma unroll
    for (int j = 0; j < 16; j++) rreg[j] = unpk(cload8(rsrc + j * 16));
    // ---- phase 2: h_cand + state update ----
    float a1 = 0.f, a2 = 0.f, a3 = 0.f;
#pragma unroll
    for (int j = 0; j < 16; j++) {
      float4 wg4 = wG[p + j * 16];
      float4 wb4 = wB[p + j * 16];
      float4 hv = hreg[j];
      float4 rv = rreg[j];
      float4 rh;
      rh.x = rv.x * hv.x; rh.y = rv.y * hv.y; rh.z = rv.z * hv.z; rh.w = rv.w * hv.w;
      a1 += dot4(wg4, rh);
      a2 += dot4(wg4, rv);
      a3 += dot4(wb4, rv);
    }
#pragma unroll
    for (int mk = 1; mk < 16; mk <<= 1) {
      a1 += __shfl_xor(a1, mk);
      a2 += __shfl_xor(a2, mk);
      a3 += __shfl_xor(a3, mk);
    }
    float pre = bf2f(gH) + bhc + rstd * a1 - m * rstd * a2 + a3;
    float hc = tanhf(pre);
    float hnew = fmaf(zv, hc - ho, ho);    // identical across the 16-lane group
    ho = hnew;
    {
      u32 mh = f2bf(hnew);
      u32 v1 = __shfl((int)mh, 16), v2 = __shfl((int)mh, 32), v3 = __shfl((int)mh, 48);
      if (ln == 0)
        cstore8(hdst, (u64)mh | ((u64)v1 << 16) | ((u64)v2 << 32) | ((u64)v3 << 48));
    }
    __syncthreads();
    if (t == 0) bar_arrive(bar, 2 * step + 1, grp);
    // ---- overlapped with barrier-2 wait: out store + next gx prefetch ----
    if (p == 0) outp[0] = hnew;
    outp += HD;
    if (step == LL - 1 && p == 0) hfin[w * HD + o] = hnew;
    gZ = gp[0]; gR = gp[HD]; gH = gp[2 * HD];
    gp += 3072;
    if (w == 0) bar_wait16(bar, 2 * step + 1, ln);
    __syncthreads();
  }
}

__global__ __launch_bounds__(256) void k_copy(const float* __restrict__ src,
    float* __restrict__ dst, int n4) {
  int i = blockIdx.x * blockDim.x + threadIdx.x;
  if (i < n4) ((float4*)dst)[i] = ((const float4*)src)[i];
}

extern "C" void kernel_launch(void* const* d_in, const int* in_sizes, int n_in,
                              void* d_out, int out_size, void* d_ws, size_t ws_size,
                              hipStream_t stream) {
  (void)in_sizes; (void)n_in; (void)out_size; (void)ws_size;
  const float* x    = (const float*)d_in[0];
  const float* h0   = (const float*)d_in[1];
  const float* wz   = (const float*)d_in[2];
  const float* bz   = (const float*)d_in[3];
  const float* wr   = (const float*)d_in[4];
  const float* br   = (const float*)d_in[5];
  const float* wh   = (const float*)d_in[6];
  const float* bh   = (const float*)d_in[7];
  const float* g_in = (const float*)d_in[8];
  const float* b_in = (const float*)d_in[9];
  const float* g_st = (const float*)d_in[10];
  const float* b_st = (const float*)d_in[11];
  const float* g_out= (const float*)d_in[12];
  const float* b_out= (const float*)d_in[13];
  float* out = (float*)d_out;

  char* ws = (char*)d_ws;
  // region A [0,32MB): xn during frontend; folded fp32 weights afterwards
  u16*   xn   = (u16*)(ws);
  float* W1p  = (float*)(ws);                       //  8 MB (after gemm)
  float* Whg  = (float*)(ws + 8388608ull);          //  4 MB
  float* Whb  = (float*)(ws + 12582912ull);         //  4 MB
  // region B: input-side bf16 weights
  u16*   win  = (u16*)(ws + 33554432ull);           //  6 MB
  // region C: gx
  u16*   gx   = (u16*)(ws + 39845888ull);           // 96 MB -> ends 140509184
  // region D: persistent small buffers
  float* Sg   = (float*)(ws + 140509184ull);        //  8 KB
  float* Sb   = (float*)(ws + 140517376ull);        //  8 KB
  u16*   hgl  = (u16*)(ws + 140525568ull);          // 16 KB (bf16 broadcast)
  u16*   rgl  = (u16*)(ws + 140558336ull);          // 16 KB (bf16 broadcast)
  u32*   bar  = (u32*)(ws + 140591104ull);          //  4 KB barrier counters
  float* hfin = (float*)(ws + 140599296ull);        // 32 KB final h fp32

  k_pack_win<<<dim3(3072), dim3(256), 0, stream>>>(wz, wr, wh, win);
  k_ln_x<<<dim3(16384), dim3(256), 0, stream>>>(x, g_in, b_in, xn);
  k_gemm<<<dim3(3072), dim3(256), 0, stream>>>(xn, win, gx);
  // after gemm: xn region is dead -> write folded recurrent weights there
  k_prep_rec<<<dim3(3072), dim3(256), 0, stream>>>(wz, wr, wh, g_st, b_st,
                                                   W1p, Whg, Whb, Sg, Sb);
  hipMemsetAsync(bar, 0, 4096, stream);
  k_init_h<<<dim3(16), dim3(256), 0, stream>>>(h0, hgl);
  k_rec<<<dim3(NBLK), dim3(NTHR), 0, stream>>>(hgl, rgl, W1p, Whg, Whb, Sg, Sb,
                                               gx, bz, br, bh, h0, out, hfin, bar);
  k_out_ln<<<dim3(16384), dim3(256), 0, stream>>>(out, g_out, b_out);
  k_copy<<<dim3(8), dim3(256), 0, stream>>>(hfin, out + (size_t)16384 * 1024, 2048);
}

// Round 7
// 29157.068 us; speedup vs baseline: 1.8141x; 1.8141x over previous
//
#include <hip/hip_runtime.h>
#include <stdint.h>
#include <math.h>

#define HD 1024
#define BB 8
#define LL 2048
#define NBLK 256
#define NTHR 512

typedef unsigned short u16;
typedef unsigned int u32;
typedef unsigned long long u64;

using bf16x8 = __attribute__((ext_vector_type(8))) short;
using f32x4  = __attribute__((ext_vector_type(4))) float;

__device__ __forceinline__ u16 f2bf(float f) {
  u32 x = __float_as_uint(f);
  x += 0x7fffu + ((x >> 16) & 1u);
  return (u16)(x >> 16);
}
__device__ __forceinline__ float bf2f(u16 u) {
  return __uint_as_float(((u32)u) << 16);
}
__device__ __forceinline__ float dot4(float4 a, float4 b) {
  return fmaf(a.x, b.x, fmaf(a.y, b.y, fmaf(a.z, b.z, a.w * b.w)));
}
__device__ __forceinline__ float sigmoidf(float x) { return 1.f / (1.f + expf(-x)); }

// ---- coherent LLC accesses via relaxed agent atomics (compiler-tracked) ----
__device__ __forceinline__ float2 cload2(const u64* p) {
  u64 v = __hip_atomic_load(p, __ATOMIC_RELAXED, __HIP_MEMORY_SCOPE_AGENT);
  float2 r;
  r.x = __uint_as_float((u32)v);
  r.y = __uint_as_float((u32)(v >> 32));
  return r;
}
__device__ __forceinline__ void cstore1(float* p, float a) {
  __hip_atomic_store((u32*)p, __float_as_uint(a), __ATOMIC_RELAXED, __HIP_MEMORY_SCOPE_AGENT);
}

// ---- barrier: 16 groups x 16 blocks; arrive=1 RMW; wait=direct 16-line poll ----
// group line (inst,g) at u32 index (inst*16+g)*16 ; 4 cycling instances, monotonic.
__device__ __forceinline__ void bar_arrive(u32* bar, int n, int grp) {
  int inst = n & 3;
  __hip_atomic_fetch_add(&bar[(inst * 16 + grp) * 16], 1u,
                         __ATOMIC_RELAXED, __HIP_MEMORY_SCOPE_AGENT);
}
__device__ __forceinline__ void bar_wait16(u32* bar, int n, int ln) {
  int inst = n & 3;
  u32 tgt = (u32)((n >> 2) + 1) * 16u;
  for (;;) {
    u32 v = tgt;
    if (ln < 16)
      v = __hip_atomic_load(&bar[(inst * 16 + ln) * 16],
                            __ATOMIC_RELAXED, __HIP_MEMORY_SCOPE_AGENT);
    if (__ballot(v >= tgt) == ~0ull) break;
    __builtin_amdgcn_s_sleep(1);
  }
}

// ---------------- input LN: x [16384,1024] f32 -> xn bf16 ----------------
__global__ __launch_bounds__(256) void k_ln_x(const float* __restrict__ x,
    const float* __restrict__ g, const float* __restrict__ b,
    u16* __restrict__ xn) {
  int row = blockIdx.x;
  int t = threadIdx.x;
  const float4* xr = (const float4*)(x + (size_t)row * HD);
  float4 v = xr[t];
  float s = v.x + v.y + v.z + v.w;
  float ss = v.x * v.x + v.y * v.y + v.z * v.z + v.w * v.w;
#pragma unroll
  for (int off = 32; off; off >>= 1) { s += __shfl_down(s, off); ss += __shfl_down(ss, off); }
  __shared__ float red[8];
  if ((t & 63) == 0) { red[t >> 6] = s; red[4 + (t >> 6)] = ss; }
  __syncthreads();
  s = red[0] + red[1] + red[2] + red[3];
  ss = red[4] + red[5] + red[6] + red[7];
  float m = s * (1.0f / HD);
  float rstd = rsqrtf(ss * (1.0f / HD) - m * m + 1e-5f);
  float4 gv = ((const float4*)g)[t];
  float4 bv = ((const float4*)b)[t];
  ushort4 o;
  o.x = f2bf((v.x - m) * rstd * gv.x + bv.x);
  o.y = f2bf((v.y - m) * rstd * gv.y + bv.y);
  o.z = f2bf((v.z - m) * rstd * gv.z + bv.z);
  o.w = f2bf((v.w - m) * rstd * gv.w + bv.w);
  *(ushort4*)(xn + (size_t)row * HD + t * 4) = o;
}

// ---------------- output LN, in place on f32 rows ----------------
__global__ __launch_bounds__(256) void k_out_ln(float* __restrict__ y,
    const float* __restrict__ g, const float* __restrict__ b) {
  int row = blockIdx.x;
  int t = threadIdx.x;
  float4* yr = (float4*)(y + (size_t)row * HD);
  float4 v = yr[t];
  float s = v.x + v.y + v.z + v.w;
  float ss = v.x * v.x + v.y * v.y + v.z * v.z + v.w * v.w;
#pragma unroll
  for (int off = 32; off; off >>= 1) { s += __shfl_down(s, off); ss += __shfl_down(ss, off); }
  __shared__ float red[8];
  if ((t & 63) == 0) { red[t >> 6] = s; red[4 + (t >> 6)] = ss; }
  __syncthreads();
  s = red[0] + red[1] + red[2] + red[3];
  ss = red[4] + red[5] + red[6] + red[7];
  float m = s * (1.0f / HD);
  float rstd = rsqrtf(ss * (1.0f / HD) - m * m + 1e-5f);
  float4 gv = ((const float4*)g)[t];
  float4 bv = ((const float4*)b)[t];
  float4 o;
  o.x = (v.x - m) * rstd * gv.x + bv.x;
  o.y = (v.y - m) * rstd * gv.y + bv.y;
  o.z = (v.z - m) * rstd * gv.z + bv.z;
  o.w = (v.w - m) * rstd * gv.w + bv.w;
  yr[t] = o;
}

// ---------------- pack input-side weights to bf16: win=[3][1024][1024] ----
__global__ __launch_bounds__(256) void k_pack_win(const float* __restrict__ wz,
    const float* __restrict__ wr, const float* __restrict__ wh,
    u16* __restrict__ win) {
  int gid = blockIdx.x;           // 0..3071
  int gate = gid >> 10, o = gid & 1023;
  const float* w = (gate == 0) ? wz : ((gate == 1) ? wr : wh);
  const float* row = w + (size_t)o * (2 * HD);
  int t = threadIdx.x;
  float4 a = ((const float4*)row)[t];
  ushort4 ua;
  ua.x = f2bf(a.x); ua.y = f2bf(a.y); ua.z = f2bf(a.z); ua.w = f2bf(a.w);
  *(ushort4*)(win + (size_t)gid * HD + t * 4) = ua;
}

// ---------------- slice recurrent weights: Wrec[g][o][k] = w_g[o, H+k] ----
__global__ __launch_bounds__(256) void k_slice_w(const float* __restrict__ wz,
    const float* __restrict__ wr, const float* __restrict__ wh,
    float* __restrict__ Wrec) {
  int gid = blockIdx.x;
  int gate = gid >> 10, o = gid & 1023;
  const float* w = (gate == 0) ? wz : ((gate == 1) ? wr : wh);
  int t = threadIdx.x;
  float4 v = ((const float4*)(w + (size_t)o * (2 * HD) + HD))[t];
  ((float4*)(Wrec + ((size_t)gate << 20) + ((size_t)o << 10)))[t] = v;
}

// ---------------- bf16 MFMA GEMM: C[16384,3072] = A[16384,1024] * B[3072,1024]^T
__global__ __launch_bounds__(256) void k_gemm(const u16* __restrict__ A,
    const u16* __restrict__ Bw, u16* __restrict__ C) {
  __shared__ u16 As[128 * 32];
  __shared__ u16 Bs[128 * 32];
  int tid = threadIdx.x;
  int bx = blockIdx.x % 24;       // N tile
  int by = blockIdx.x / 24;       // M tile
  int m0 = by * 128, n0 = bx * 128;
  int lane = tid & 63, wave = tid >> 6;
  int wr = wave >> 1, wc = wave & 1;
  int rl = lane & 15, kq = (lane >> 4) * 8;
  f32x4 acc[4][4] = {};
  int srow = tid >> 2, skb = (tid & 3) * 8;
  for (int k0 = 0; k0 < 1024; k0 += 32) {
    __syncthreads();
#pragma unroll
    for (int i = 0; i < 2; i++) {
      int row = srow + i * 64;
      uint4 av = *(const uint4*)(A + (size_t)(m0 + row) * 1024 + k0 + skb);
      *(uint4*)(As + row * 32 + skb) = av;
      uint4 bv = *(const uint4*)(Bw + (size_t)(n0 + row) * 1024 + k0 + skb);
      *(uint4*)(Bs + row * 32 + skb) = bv;
    }
    __syncthreads();
    bf16x8 af[4], bg[4];
#pragma unroll
    for (int mi = 0; mi < 4; mi++)
      af[mi] = *(const bf16x8*)(As + (wr * 64 + mi * 16 + rl) * 32 + kq);
#pragma unroll
    for (int ni = 0; ni < 4; ni++)
      bg[ni] = *(const bf16x8*)(Bs + (wc * 64 + ni * 16 + rl) * 32 + kq);
#pragma unroll
    for (int mi = 0; mi < 4; mi++)
#pragma unroll
      for (int ni = 0; ni < 4; ni++)
        acc[mi][ni] = __builtin_amdgcn_mfma_f32_16x16x32_bf16(af[mi], bg[ni], acc[mi][ni], 0, 0, 0);
  }
  int rowq = (lane >> 4) * 4;
#pragma unroll
  for (int mi = 0; mi < 4; mi++)
#pragma unroll
    for (int ni = 0; ni < 4; ni++)
#pragma unroll
      for (int r = 0; r < 4; r++) {
        int row = m0 + wr * 64 + mi * 16 + rowq + r;
        int col = n0 + wc * 64 + ni * 16 + rl;
        C[(size_t)row * 3072 + col] = f2bf(acc[mi][ni][r]);
      }
}

// ---------------- persistent recurrence kernel ----------------------------
// 256 blocks x 512 threads; block bl owns outputs [bl*4, bl*4+4) per gate.
// Wave w owns batch w: stages h/r global->LDS (coalesced, once), computes LN
// stats + explicit hn. Lane (oi,p): output o0+oi, k-slice lane p (16 lanes).
// hn slice register-cached; z overlapped with barrier-1; gx prefetched.
__global__ __launch_bounds__(NTHR, 1) void k_rec(
    float* __restrict__ hglob, float* __restrict__ rglob,
    const float* __restrict__ Wrec, const u16* __restrict__ gx,
    const float* __restrict__ bz, const float* __restrict__ br,
    const float* __restrict__ bh, const float* __restrict__ g_st,
    const float* __restrict__ b_st, const float* __restrict__ h0,
    float* __restrict__ out, float* __restrict__ hfin,
    u32* __restrict__ bar) {
  __shared__ float hn_s[BB * HD];
  __shared__ float r_s[BB * HD];
  const int t = threadIdx.x;
  const int bl = blockIdx.x;
  const int grp = bl >> 4;
  const int o0 = bl * 4;
  const int w = t >> 6, ln = t & 63;
  const int p = ln & 15, oi = ln >> 4;
  const int o = o0 + oi;

  const float4* wZ = (const float4*)(Wrec + ((size_t)o << 10));
  const float4* wR = (const float4*)(Wrec + (1u << 20) + ((size_t)o << 10));
  const float4* wH = (const float4*)(Wrec + (2u << 20) + ((size_t)o << 10));
  const float biZ = bz[o], biR = br[o], bhc = bh[o];
  const u16* gp = gx + ((size_t)w * LL) * 3072 + o;   // +0:z, +HD:r, +2HD:h
  float* outp = out + ((size_t)w * LL) * HD + o;
  const u64* hsrc = (const u64*)hglob + (size_t)w * 512 + ln;
  const u64* rsrc = (const u64*)rglob + (size_t)w * 512 + ln;
  const float4* hv4 = (const float4*)(hn_s + w * HD);
  const float4* rv4 = (const float4*)(r_s + w * HD);

  // gamma/beta slices for this thread's staging partition (constant)
  float2 gam[8], bet[8];
#pragma unroll
  for (int i = 0; i < 8; i++) {
    gam[i] = ((const float2*)g_st)[ln + 64 * i];
    bet[i] = ((const float2*)b_st)[ln + 64 * i];
  }
  float ho = h0[w * HD + o];        // master state, replicated in 16-lane group
  u16 gZ = gp[0], gR = gp[HD], gH = gp[2 * HD];   // step-0 gx prefetch
  gp += 3072;

  for (int step = 0; step < LL; step++) {
    // ---- stage h (wave-coalesced sc1) + LN stats + explicit hn -> LDS ----
    float2 h2[8];
#pragma unroll
    for (int i = 0; i < 8; i++) h2[i] = cload2(hsrc + 64 * i);
    float s = 0.f, ss = 0.f;
#pragma unroll
    for (int i = 0; i < 8; i++) {
      s += h2[i].x + h2[i].y;
      ss = fmaf(h2[i].x, h2[i].x, fmaf(h2[i].y, h2[i].y, ss));
    }
#pragma unroll
    for (int mk = 1; mk < 64; mk <<= 1) { s += __shfl_xor(s, mk); ss += __shfl_xor(ss, mk); }
    float m = s * (1.0f / HD);
    float rstd = rsqrtf(ss * (1.0f / HD) - m * m + 1e-5f);
    float2* hw = (float2*)(hn_s + w * HD) + ln;
#pragma unroll
    for (int i = 0; i < 8; i++) {
      float2 hn;
      hn.x = fmaf((h2[i].x - m) * rstd, gam[i].x, bet[i].x);
      hn.y = fmaf((h2[i].y - m) * rstd, gam[i].y, bet[i].y);
      hw[64 * i] = hn;
    }
    __syncthreads();
    // ---- r gate (register-cache hn slice on this pass), publish, arrive ----
    float4 hreg[16];
    float accR = 0.f;
#pragma unroll
    for (int j = 0; j < 16; j++) {
      hreg[j] = hv4[p + j * 16];
      accR += dot4(wR[p + j * 16], hreg[j]);
    }
    accR += __shfl_xor(accR, 1);
    accR += __shfl_xor(accR, 2);
    accR += __shfl_xor(accR, 4);
    accR += __shfl_xor(accR, 8);
    float sigR = sigmoidf(accR + bf2f(gR) + biR);
    if (p == 0) cstore1(rglob + w * HD + o, sigR);
    __syncthreads();                       // drains sc1 store (vmcnt 0)
    if (t == 0) bar_arrive(bar, 2 * step, grp);
    // ---- z gate from registers, overlapped with barrier-1 wait ----
    float accZ = 0.f;
#pragma unroll
    for (int j = 0; j < 16; j++) accZ += dot4(wZ[p + j * 16], hreg[j]);
    accZ += __shfl_xor(accZ, 1);
    accZ += __shfl_xor(accZ, 2);
    accZ += __shfl_xor(accZ, 4);
    accZ += __shfl_xor(accZ, 8);
    float zv = sigmoidf(accZ + bf2f(gZ) + biZ);
    if (w == 0) bar_wait16(bar, 2 * step, ln);
    __syncthreads();
    // ---- stage r (wave-coalesced sc1) -> LDS ----
    float2 r2[8];
#pragma unroll
    for (int i = 0; i < 8; i++) r2[i] = cload2(rsrc + 64 * i);
    float2* rw = (float2*)(r_s + w * HD) + ln;
#pragma unroll
    for (int i = 0; i < 8; i++) rw[64 * i] = r2[i];
    __syncthreads();
    // ---- phase 2: single dot Wh . (r * hn) ----
    float a1 = 0.f;
#pragma unroll
    for (int j = 0; j < 16; j++) {
      float4 rv = rv4[p + j * 16];
      float4 u;
      u.x = rv.x * hreg[j].x; u.y = rv.y * hreg[j].y;
      u.z = rv.z * hreg[j].z; u.w = rv.w * hreg[j].w;
      a1 += dot4(wH[p + j * 16], u);
    }
    a1 += __shfl_xor(a1, 1);
    a1 += __shfl_xor(a1, 2);
    a1 += __shfl_xor(a1, 4);
    a1 += __shfl_xor(a1, 8);
    float hc = tanhf(a1 + bf2f(gH) + bhc);
    float hnew = fmaf(zv, hc - ho, ho);    // identical across the 16-lane group
    ho = hnew;
    if (p == 0) cstore1(hglob + w * HD + o, hnew);
    __syncthreads();
    if (t == 0) bar_arrive(bar, 2 * step + 1, grp);
    // ---- overlapped with barrier-2 wait: out store + next gx prefetch ----
    if (p == 0) outp[0] = hnew;
    outp += HD;
    if (step == LL - 1 && p == 0) hfin[w * HD + o] = hnew;
    gZ = gp[0]; gR = gp[HD]; gH = gp[2 * HD];
    gp += 3072;
    if (w == 0) bar_wait16(bar, 2 * step + 1, ln);
    __syncthreads();
  }
}

__global__ __launch_bounds__(256) void k_copy(const float* __restrict__ src,
    float* __restrict__ dst, int n4) {
  int i = blockIdx.x * blockDim.x + threadIdx.x;
  if (i < n4) ((float4*)dst)[i] = ((const float4*)src)[i];
}

extern "C" void kernel_launch(void* const* d_in, const int* in_sizes, int n_in,
                              void* d_out, int out_size, void* d_ws, size_t ws_size,
                              hipStream_t stream) {
  (void)in_sizes; (void)n_in; (void)out_size; (void)ws_size;
  const float* x    = (const float*)d_in[0];
  const float* h0   = (const float*)d_in[1];
  const float* wz   = (const float*)d_in[2];
  const float* bz   = (const float*)d_in[3];
  const float* wr   = (const float*)d_in[4];
  const float* br   = (const float*)d_in[5];
  const float* wh   = (const float*)d_in[6];
  const float* bh   = (const float*)d_in[7];
  const float* g_in = (const float*)d_in[8];
  const float* b_in = (const float*)d_in[9];
  const float* g_st = (const float*)d_in[10];
  const float* b_st = (const float*)d_in[11];
  const float* g_out= (const float*)d_in[12];
  const float* b_out= (const float*)d_in[13];
  float* out = (float*)d_out;

  char* ws = (char*)d_ws;
  // region A [0,32MB): xn during frontend; raw recurrent fp32 weights after
  u16*   xn   = (u16*)(ws);
  float* Wrec = (float*)(ws);                       // 12 MB (after gemm)
  // region B: input-side bf16 weights
  u16*   win  = (u16*)(ws + 33554432ull);           //  6 MB
  // region C: gx
  u16*   gx   = (u16*)(ws + 39845888ull);           // 96 MB -> ends 140509184
  // region D: persistent small buffers
  float* hgl  = (float*)(ws + 140509184ull);        // 32 KB fp32 broadcast
  float* rgl  = (float*)(ws + 140541952ull);        // 32 KB fp32 broadcast
  u32*   bar  = (u32*)(ws + 140574720ull);          //  4 KB barrier counters
  float* hfin = (float*)(ws + 140578816ull);        // 32 KB final h fp32

  k_pack_win<<<dim3(3072), dim3(256), 0, stream>>>(wz, wr, wh, win);
  k_ln_x<<<dim3(16384), dim3(256), 0, stream>>>(x, g_in, b_in, xn);
  k_gemm<<<dim3(3072), dim3(256), 0, stream>>>(xn, win, gx);
  // after gemm: xn region is dead -> write raw recurrent weights there
  k_slice_w<<<dim3(3072), dim3(256), 0, stream>>>(wz, wr, wh, Wrec);
  hipMemsetAsync(bar, 0, 4096, stream);
  hipMemcpyAsync(hgl, h0, (size_t)BB * HD * sizeof(float),
                 hipMemcpyDeviceToDevice, stream);
  k_rec<<<dim3(NBLK), dim3(NTHR), 0, stream>>>(hgl, rgl, Wrec, gx, bz, br, bh,
                                               g_st, b_st, h0, out, hfin, bar);
  k_out_ln<<<dim3(16384), dim3(256), 0, stream>>>(out, g_out, b_out);
  k_copy<<<dim3(8), dim3(256), 0, stream>>>(hfin, out + (size_t)16384 * 1024, 2048);
}

// Round 8
// 10872.426 us; speedup vs baseline: 4.8649x; 2.6817x over previous
//
#include <hip/hip_runtime.h>
#include <stdint.h>
#include <math.h>

#define HD 1024
#define BB 8
#define LL 2048
#define NBLK 256
#define NTHR 512

typedef unsigned short u16;
typedef unsigned int u32;
typedef unsigned long long u64;

using bf16x8 = __attribute__((ext_vector_type(8))) short;
using f32x4  = __attribute__((ext_vector_type(4))) float;

__device__ __forceinline__ u16 f2bf(float f) {
  u32 x = __float_as_uint(f);
  x += 0x7fffu + ((x >> 16) & 1u);
  return (u16)(x >> 16);
}
__device__ __forceinline__ float bf2f(u16 u) {
  return __uint_as_float(((u32)u) << 16);
}
__device__ __forceinline__ float dot4(float4 a, float4 b) {
  return fmaf(a.x, b.x, fmaf(a.y, b.y, fmaf(a.z, b.z, a.w * b.w)));
}
__device__ __forceinline__ float sigmoidf(float x) { return 1.f / (1.f + expf(-x)); }

// ---- coherent LLC accesses via relaxed agent atomics (compiler-tracked) ----
__device__ __forceinline__ float2 cload2(const u64* p) {
  u64 v = __hip_atomic_load(p, __ATOMIC_RELAXED, __HIP_MEMORY_SCOPE_AGENT);
  float2 r;
  r.x = __uint_as_float((u32)v);
  r.y = __uint_as_float((u32)(v >> 32));
  return r;
}
__device__ __forceinline__ void cstore1(float* p, float a) {
  __hip_atomic_store((u32*)p, __float_as_uint(a), __ATOMIC_RELAXED, __HIP_MEMORY_SCOPE_AGENT);
}

// ---- per-batch barrier: 32 blocks on ONE line; monotonic, 4 cycling insts ----
// line for (batch b, inst) at u32 index (b*4+inst)*16 (64B apart).
__device__ __forceinline__ void bar_arrive(u32* bar, int b, int n) {
  int inst = n & 3;
  __hip_atomic_fetch_add(&bar[(b * 4 + inst) * 16], 1u,
                         __ATOMIC_RELAXED, __HIP_MEMORY_SCOPE_AGENT);
}
__device__ __forceinline__ void bar_wait(u32* bar, int b, int n) {
  int inst = n & 3;
  u32 tgt = (u32)((n >> 2) + 1) * 32u;
  while (__hip_atomic_load(&bar[(b * 4 + inst) * 16],
                           __ATOMIC_RELAXED, __HIP_MEMORY_SCOPE_AGENT) < tgt)
    __builtin_amdgcn_s_sleep(1);
}

// ---------------- input LN: x [16384,1024] f32 -> xn bf16 ----------------
__global__ __launch_bounds__(256) void k_ln_x(const float* __restrict__ x,
    const float* __restrict__ g, const float* __restrict__ b,
    u16* __restrict__ xn) {
  int row = blockIdx.x;
  int t = threadIdx.x;
  const float4* xr = (const float4*)(x + (size_t)row * HD);
  float4 v = xr[t];
  float s = v.x + v.y + v.z + v.w;
  float ss = v.x * v.x + v.y * v.y + v.z * v.z + v.w * v.w;
#pragma unroll
  for (int off = 32; off; off >>= 1) { s += __shfl_down(s, off); ss += __shfl_down(ss, off); }
  __shared__ float red[8];
  if ((t & 63) == 0) { red[t >> 6] = s; red[4 + (t >> 6)] = ss; }
  __syncthreads();
  s = red[0] + red[1] + red[2] + red[3];
  ss = red[4] + red[5] + red[6] + red[7];
  float m = s * (1.0f / HD);
  float rstd = rsqrtf(ss * (1.0f / HD) - m * m + 1e-5f);
  float4 gv = ((const float4*)g)[t];
  float4 bv = ((const float4*)b)[t];
  ushort4 o;
  o.x = f2bf((v.x - m) * rstd * gv.x + bv.x);
  o.y = f2bf((v.y - m) * rstd * gv.y + bv.y);
  o.z = f2bf((v.z - m) * rstd * gv.z + bv.z);
  o.w = f2bf((v.w - m) * rstd * gv.w + bv.w);
  *(ushort4*)(xn + (size_t)row * HD + t * 4) = o;
}

// ---------------- output LN, in place on f32 rows ----------------
__global__ __launch_bounds__(256) void k_out_ln(float* __restrict__ y,
    const float* __restrict__ g, const float* __restrict__ b) {
  int row = blockIdx.x;
  int t = threadIdx.x;
  float4* yr = (float4*)(y + (size_t)row * HD);
  float4 v = yr[t];
  float s = v.x + v.y + v.z + v.w;
  float ss = v.x * v.x + v.y * v.y + v.z * v.z + v.w * v.w;
#pragma unroll
  for (int off = 32; off; off >>= 1) { s += __shfl_down(s, off); ss += __shfl_down(ss, off); }
  __shared__ float red[8];
  if ((t & 63) == 0) { red[t >> 6] = s; red[4 + (t >> 6)] = ss; }
  __syncthreads();
  s = red[0] + red[1] + red[2] + red[3];
  ss = red[4] + red[5] + red[6] + red[7];
  float m = s * (1.0f / HD);
  float rstd = rsqrtf(ss * (1.0f / HD) - m * m + 1e-5f);
  float4 gv = ((const float4*)g)[t];
  float4 bv = ((const float4*)b)[t];
  float4 o;
  o.x = (v.x - m) * rstd * gv.x + bv.x;
  o.y = (v.y - m) * rstd * gv.y + bv.y;
  o.z = (v.z - m) * rstd * gv.z + bv.z;
  o.w = (v.w - m) * rstd * gv.w + bv.w;
  yr[t] = o;
}

// ---------------- pack input-side weights to bf16: win=[3][1024][1024] ----
__global__ __launch_bounds__(256) void k_pack_win(const float* __restrict__ wz,
    const float* __restrict__ wr, const float* __restrict__ wh,
    u16* __restrict__ win) {
  int gid = blockIdx.x;           // 0..3071
  int gate = gid >> 10, o = gid & 1023;
  const float* w = (gate == 0) ? wz : ((gate == 1) ? wr : wh);
  const float* row = w + (size_t)o * (2 * HD);
  int t = threadIdx.x;
  float4 a = ((const float4*)row)[t];
  ushort4 ua;
  ua.x = f2bf(a.x); ua.y = f2bf(a.y); ua.z = f2bf(a.z); ua.w = f2bf(a.w);
  *(ushort4*)(win + (size_t)gid * HD + t * 4) = ua;
}

// ---------------- slice recurrent weights: Wrec[g][o][k] = w_g[o, H+k] ----
__global__ __launch_bounds__(256) void k_slice_w(const float* __restrict__ wz,
    const float* __restrict__ wr, const float* __restrict__ wh,
    float* __restrict__ Wrec) {
  int gid = blockIdx.x;
  int gate = gid >> 10, o = gid & 1023;
  const float* w = (gate == 0) ? wz : ((gate == 1) ? wr : wh);
  int t = threadIdx.x;
  float4 v = ((const float4*)(w + (size_t)o * (2 * HD) + HD))[t];
  ((float4*)(Wrec + ((size_t)gate << 20) + ((size_t)o << 10)))[t] = v;
}

// ---------------- bf16 MFMA GEMM: C[16384,3072] = A[16384,1024] * B[3072,1024]^T
__global__ __launch_bounds__(256) void k_gemm(const u16* __restrict__ A,
    const u16* __restrict__ Bw, u16* __restrict__ C) {
  __shared__ u16 As[128 * 32];
  __shared__ u16 Bs[128 * 32];
  int tid = threadIdx.x;
  int bx = blockIdx.x % 24;       // N tile
  int by = blockIdx.x / 24;       // M tile
  int m0 = by * 128, n0 = bx * 128;
  int lane = tid & 63, wave = tid >> 6;
  int wr = wave >> 1, wc = wave & 1;
  int rl = lane & 15, kq = (lane >> 4) * 8;
  f32x4 acc[4][4] = {};
  int srow = tid >> 2, skb = (tid & 3) * 8;
  for (int k0 = 0; k0 < 1024; k0 += 32) {
    __syncthreads();
#pragma unroll
    for (int i = 0; i < 2; i++) {
      int row = srow + i * 64;
      uint4 av = *(const uint4*)(A + (size_t)(m0 + row) * 1024 + k0 + skb);
      *(uint4*)(As + row * 32 + skb) = av;
      uint4 bv = *(const uint4*)(Bw + (size_t)(n0 + row) * 1024 + k0 + skb);
      *(uint4*)(Bs + row * 32 + skb) = bv;
    }
    __syncthreads();
    bf16x8 af[4], bg[4];
#pragma unroll
    for (int mi = 0; mi < 4; mi++)
      af[mi] = *(const bf16x8*)(As + (wr * 64 + mi * 16 + rl) * 32 + kq);
#pragma unroll
    for (int ni = 0; ni < 4; ni++)
      bg[ni] = *(const bf16x8*)(Bs + (wc * 64 + ni * 16 + rl) * 32 + kq);
#pragma unroll
    for (int mi = 0; mi < 4; mi++)
#pragma unroll
      for (int ni = 0; ni < 4; ni++)
        acc[mi][ni] = __builtin_amdgcn_mfma_f32_16x16x32_bf16(af[mi], bg[ni], acc[mi][ni], 0, 0, 0);
  }
  int rowq = (lane >> 4) * 4;
#pragma unroll
  for (int mi = 0; mi < 4; mi++)
#pragma unroll
    for (int ni = 0; ni < 4; ni++)
#pragma unroll
      for (int r = 0; r < 4; r++) {
        int row = m0 + wr * 64 + mi * 16 + rowq + r;
        int col = n0 + wc * 64 + ni * 16 + rl;
        C[(size_t)row * 3072 + col] = f2bf(acc[mi][ni][r]);
      }
}

// ---------------- persistent recurrence kernel, batch-split ----------------
// 256 blocks = 8 batches x 32 output-blocks; bid = b*32 + ob (siblings sharing
// weights land on one XCD under round-robin %8). Block handles outputs
// [ob*32, ob*32+32) of batch b for all gates. 64-lane dots: thread's 16-elem
// slice read once from LDS, reused for z+r; phase2 = single dot Wh.(r*hn).
__global__ __launch_bounds__(NTHR, 1) void k_rec(
    float* __restrict__ hglob, float* __restrict__ rglob,
    const float* __restrict__ Wrec, const u16* __restrict__ gx,
    const float* __restrict__ bz, const float* __restrict__ br,
    const float* __restrict__ bh, const float* __restrict__ g_st,
    const float* __restrict__ b_st, const float* __restrict__ h0,
    float* __restrict__ out, u32* __restrict__ bar) {
  __shared__ float hn_s[HD];
  __shared__ float u_s[HD];
  __shared__ float2 red2[8];
  const int t = threadIdx.x;
  const int bid = blockIdx.x;
  const int b = bid >> 5, ob = bid & 31;
  const int w8 = t >> 6, ln = t & 63;
  const int q = ln & 3;
  const int o_fin = ob * 32 + w8 * 4 + q;       // output handled by lanes ln<4

  // weight slice bases: thread covers elems [ln*16, ln*16+16) of each row
  const float4* wz4 = (const float4*)(Wrec + (size_t)(ob * 32 + w8 * 4) * HD) + ln * 4;
  const float4* wr4 = wz4 + (1u << 18);
  const float4* wh4 = wz4 + (2u << 18);
  const float biZ = bz[o_fin], biR = br[o_fin], bhc = bh[o_fin];
  const float2 gm2 = ((const float2*)g_st)[t];
  const float2 bt2 = ((const float2*)b_st)[t];
  const u16* gp = gx + ((size_t)b * LL) * 3072 + o_fin;  // +0:z +1024:r +2048:h
  float* outp = out + ((size_t)b * LL) * HD + o_fin;
  const u64* hsrc = (const u64*)(hglob + (size_t)b * HD) + t;
  const u64* rsrc = (const u64*)(rglob + (size_t)b * HD) + t;
  float* hpub = hglob + b * HD + o_fin;
  float* rpub = rglob + b * HD + o_fin;

  float ho = h0[b * HD + o_fin];                 // master state (lanes ln<4)
  u16 gZ = gp[0], gR = gp[1024], gH = gp[2048];  // step-0 gx prefetch
  gp += 3072;

  for (int step = 0; step < LL; step++) {
    // ---- stage h (1 cload2/thread) + block LN stats + hn -> LDS ----
    float2 h2 = cload2(hsrc);
    float s = h2.x + h2.y;
    float ss = fmaf(h2.x, h2.x, h2.y * h2.y);
#pragma unroll
    for (int mk = 1; mk < 64; mk <<= 1) { s += __shfl_xor(s, mk); ss += __shfl_xor(ss, mk); }
    if (ln == 0) { float2 rv; rv.x = s; rv.y = ss; red2[w8] = rv; }
    __syncthreads();
    s = 0.f; ss = 0.f;
#pragma unroll
    for (int i = 0; i < 8; i++) { float2 rv = red2[i]; s += rv.x; ss += rv.y; }
    float m = s * (1.0f / HD);
    float rstd = rsqrtf(ss * (1.0f / HD) - m * m + 1e-5f);
    float2 hn;
    hn.x = fmaf((h2.x - m) * rstd, gm2.x, bt2.x);
    hn.y = fmaf((h2.y - m) * rstd, gm2.y, bt2.y);
    ((float2*)hn_s)[t] = hn;
    __syncthreads();
    // ---- load hn slice once (4 b128), reused for r and z passes ----
    float4 hsl0 = ((const float4*)hn_s)[ln * 4 + 0];
    float4 hsl1 = ((const float4*)hn_s)[ln * 4 + 1];
    float4 hsl2 = ((const float4*)hn_s)[ln * 4 + 2];
    float4 hsl3 = ((const float4*)hn_s)[ln * 4 + 3];
    // ---- r gate: 4 outputs per wave, 64-lane dots ----
    float a0 = 0.f, a1 = 0.f, a2 = 0.f, a3 = 0.f;
#pragma unroll
    for (int jj = 0; jj < 4; jj++) {
      float4 h4 = (jj == 0) ? hsl0 : ((jj == 1) ? hsl1 : ((jj == 2) ? hsl2 : hsl3));
      a0 += dot4(wr4[jj], h4);
      a1 += dot4(wr4[256 + jj], h4);
      a2 += dot4(wr4[512 + jj], h4);
      a3 += dot4(wr4[768 + jj], h4);
    }
#pragma unroll
    for (int mk = 1; mk < 64; mk <<= 1) {
      a0 += __shfl_xor(a0, mk); a1 += __shfl_xor(a1, mk);
      a2 += __shfl_xor(a2, mk); a3 += __shfl_xor(a3, mk);
    }
    if (ln < 4) {
      float av = (q == 0) ? a0 : ((q == 1) ? a1 : ((q == 2) ? a2 : a3));
      cstore1(rpub, sigmoidf(av + bf2f(gR) + biR));
    }
    __syncthreads();                  // drains sc1 store before arrive
    if (t == 0) bar_arrive(bar, b, 2 * step);
    // ---- z gate from the same hn slice, overlapped with barrier-1 wait ----
    a0 = 0.f; a1 = 0.f; a2 = 0.f; a3 = 0.f;
#pragma unroll
    for (int jj = 0; jj < 4; jj++) {
      float4 h4 = (jj == 0) ? hsl0 : ((jj == 1) ? hsl1 : ((jj == 2) ? hsl2 : hsl3));
      a0 += dot4(wz4[jj], h4);
      a1 += dot4(wz4[256 + jj], h4);
      a2 += dot4(wz4[512 + jj], h4);
      a3 += dot4(wz4[768 + jj], h4);
    }
#pragma unroll
    for (int mk = 1; mk < 64; mk <<= 1) {
      a0 += __shfl_xor(a0, mk); a1 += __shfl_xor(a1, mk);
      a2 += __shfl_xor(a2, mk); a3 += __shfl_xor(a3, mk);
    }
    float zv = 0.f;
    if (ln < 4) {
      float av = (q == 0) ? a0 : ((q == 1) ? a1 : ((q == 2) ? a2 : a3));
      zv = sigmoidf(av + bf2f(gZ) + biZ);
    }
    if (t == 0) bar_wait(bar, b, 2 * step);
    __syncthreads();
    // ---- stage r, compute u = r*hn -> LDS ----
    float2 rr = cload2(rsrc);
    float2 uu;
    uu.x = rr.x * hn.x;
    uu.y = rr.y * hn.y;
    ((float2*)u_s)[t] = uu;
    __syncthreads();
    // ---- phase 2: single dot Wh . u ----
    a0 = 0.f; a1 = 0.f; a2 = 0.f; a3 = 0.f;
#pragma unroll
    for (int jj = 0; jj < 4; jj++) {
      float4 u4 = ((const float4*)u_s)[ln * 4 + jj];
      a0 += dot4(wh4[jj], u4);
      a1 += dot4(wh4[256 + jj], u4);
      a2 += dot4(wh4[512 + jj], u4);
      a3 += dot4(wh4[768 + jj], u4);
    }
#pragma unroll
    for (int mk = 1; mk < 64; mk <<= 1) {
      a0 += __shfl_xor(a0, mk); a1 += __shfl_xor(a1, mk);
      a2 += __shfl_xor(a2, mk); a3 += __shfl_xor(a3, mk);
    }
    float hnew = 0.f;
    if (ln < 4) {
      float av = (q == 0) ? a0 : ((q == 1) ? a1 : ((q == 2) ? a2 : a3));
      float hc = tanhf(av + bf2f(gH) + bhc);
      hnew = fmaf(zv, hc - ho, ho);
      ho = hnew;
      cstore1(hpub, hnew);
    }
    __syncthreads();                  // drains sc1 store before arrive
    if (t == 0) bar_arrive(bar, b, 2 * step + 1);
    // ---- overlapped with barrier-2 wait: out store + next gx prefetch ----
    if (ln < 4) outp[0] = hnew;
    outp += HD;
    gZ = gp[0]; gR = gp[1024]; gH = gp[2048];
    gp += 3072;
    if (t == 0) bar_wait(bar, b, 2 * step + 1);
    __syncthreads();
  }
}

__global__ __launch_bounds__(256) void k_copy(const float* __restrict__ src,
    float* __restrict__ dst, int n4) {
  int i = blockIdx.x * blockDim.x + threadIdx.x;
  if (i < n4) ((float4*)dst)[i] = ((const float4*)src)[i];
}

extern "C" void kernel_launch(void* const* d_in, const int* in_sizes, int n_in,
                              void* d_out, int out_size, void* d_ws, size_t ws_size,
                              hipStream_t stream) {
  (void)in_sizes; (void)n_in; (void)out_size; (void)ws_size;
  const float* x    = (const float*)d_in[0];
  const float* h0   = (const float*)d_in[1];
  const float* wz   = (const float*)d_in[2];
  const float* bz   = (const float*)d_in[3];
  const float* wr   = (const float*)d_in[4];
  const float* br   = (const float*)d_in[5];
  const float* wh   = (const float*)d_in[6];
  const float* bh   = (const float*)d_in[7];
  const float* g_in = (const float*)d_in[8];
  const float* b_in = (const float*)d_in[9];
  const float* g_st = (const float*)d_in[10];
  const float* b_st = (const float*)d_in[11];
  const float* g_out= (const float*)d_in[12];
  const float* b_out= (const float*)d_in[13];
  float* out = (float*)d_out;

  char* ws = (char*)d_ws;
  // region A [0,32MB): xn during frontend; raw recurrent fp32 weights after
  u16*   xn   = (u16*)(ws);
  float* Wrec = (float*)(ws);                       // 12 MB (after gemm)
  // region B: input-side bf16 weights
  u16*   win  = (u16*)(ws + 33554432ull);           //  6 MB
  // region C: gx
  u16*   gx   = (u16*)(ws + 39845888ull);           // 96 MB -> ends 140509184
  // region D: persistent small buffers
  float* hgl  = (float*)(ws + 140509184ull);        // 32 KB fp32 state
  float* rgl  = (float*)(ws + 140541952ull);        // 32 KB fp32 r broadcast
  u32*   bar  = (u32*)(ws + 140574720ull);          //  4 KB barrier counters

  k_pack_win<<<dim3(3072), dim3(256), 0, stream>>>(wz, wr, wh, win);
  k_ln_x<<<dim3(16384), dim3(256), 0, stream>>>(x, g_in, b_in, xn);
  k_gemm<<<dim3(3072), dim3(256), 0, stream>>>(xn, win, gx);
  // after gemm: xn region is dead -> write raw recurrent weights there
  k_slice_w<<<dim3(3072), dim3(256), 0, stream>>>(wz, wr, wh, Wrec);
  hipMemsetAsync(bar, 0, 4096, stream);
  hipMemcpyAsync(hgl, h0, (size_t)BB * HD * sizeof(float),
                 hipMemcpyDeviceToDevice, stream);
  k_rec<<<dim3(NBLK), dim3(NTHR), 0, stream>>>(hgl, rgl, Wrec, gx, bz, br, bh,
                                               g_st, b_st, h0, out, bar);
  k_out_ln<<<dim3(16384), dim3(256), 0, stream>>>(out, g_out, b_out);
  k_copy<<<dim3(8), dim3(256), 0, stream>>>(hgl, out + (size_t)16384 * 1024, 2048);
}